// Round 17
// baseline (845.076 us; speedup 1.0000x reference)
//
#include <hip/hip_runtime.h>
#include <hip/hip_bf16.h>

#define C_IN  512
#define C_HID 256
#define C_OUT 64
#define K_STEPS 10
#define ALPHA 0.1f

#define BKT_SHIFT 9          // 512 nodes per bucket
#define BKT_NODES 512
#define BCAP 24576           // per-bucket edge capacity (mean 16384 -> huge margin)
#define EPB 4096             // edges per block in pass A (16 per thread)

typedef _Float16 half8 __attribute__((ext_vector_type(8)));
typedef float f32x4 __attribute__((ext_vector_type(4)));

// ---------------------------------------------------------------------------
// CSR build via two-level counting sort (write-locality-friendly)
// ---------------------------------------------------------------------------

__global__ __launch_bounds__(256) void k_bucketA(
    const int* __restrict__ src, const int* __restrict__ dst, int E,
    int* __restrict__ bcursor, long long* __restrict__ bedges, int nbkt)
{
    __shared__ int lcount[256];
    __shared__ int lbase[256];
    int t = threadIdx.x;
    int base = blockIdx.x * EPB;
    for (int i = t; i < nbkt; i += 256) lcount[i] = 0;
    __syncthreads();

    int       mybkt[16];
    int       myoff[16];
    long long mypk[16];
    #pragma unroll
    for (int j = 0; j < 16; j++) {
        int e = base + j * 256 + t;          // coalesced
        if (e < E) {
            int s = src[e], d = dst[e];
            int b = d >> BKT_SHIFT;
            mybkt[j] = b;
            mypk[j]  = ((long long)d << 32) | (unsigned int)s;
            myoff[j] = atomicAdd(&lcount[b], 1);
        } else {
            mybkt[j] = -1;
        }
    }
    __syncthreads();
    for (int i = t; i < nbkt; i += 256)
        lbase[i] = lcount[i] ? atomicAdd(&bcursor[i], lcount[i]) : 0;
    __syncthreads();
    #pragma unroll
    for (int j = 0; j < 16; j++) {
        if (mybkt[j] >= 0) {
            int p = lbase[mybkt[j]] + myoff[j];
            bedges[(size_t)mybkt[j] * BCAP + p] = mypk[j];
        }
    }
}

// counts + dinv fused (dinv = 1/sqrt(deg+1), deg from LDS histogram)
__global__ __launch_bounds__(256) void k_bcount(
    const int* __restrict__ bcursor, const long long* __restrict__ bedges,
    int* __restrict__ counts, float* __restrict__ dinv, int N)
{
    __shared__ int lcnt[BKT_NODES];
    int b = blockIdx.x, t = threadIdx.x;
    int nodebase = b << BKT_SHIFT;
    for (int i = t; i < BKT_NODES; i += 256) lcnt[i] = 0;
    __syncthreads();
    int cnt = bcursor[b];
    const long long* be = bedges + (size_t)b * BCAP;
    for (int i = t; i < cnt; i += 256) {
        int d = (int)(be[i] >> 32);
        atomicAdd(&lcnt[d - nodebase], 1);
    }
    __syncthreads();
    for (int i = t; i < BKT_NODES; i += 256) {
        int node = nodebase + i;
        if (node < N) {
            int c = lcnt[i];
            counts[node] = c;
            dinv[node] = 1.0f / sqrtf((float)(c + 1));
        }
    }
}

__global__ __launch_bounds__(256) void k_bscatter(
    const int* __restrict__ bcursor, const long long* __restrict__ bedges,
    const int* __restrict__ rowptr, int* __restrict__ csr_src, int N)
{
    __shared__ int lcur[BKT_NODES];
    int b = blockIdx.x, t = threadIdx.x;
    int nodebase = b << BKT_SHIFT;
    for (int i = t; i < BKT_NODES; i += 256) {
        int node = nodebase + i;
        lcur[i] = (node < N) ? rowptr[node] : 0;
    }
    __syncthreads();
    int cnt = bcursor[b];
    const long long* be = bedges + (size_t)b * BCAP;
    for (int i = t; i < cnt; i += 256) {
        long long pk = be[i];
        int d = (int)(pk >> 32);
        int s = (int)pk;
        int p = atomicAdd(&lcur[d - nodebase], 1);
        csr_src[p] = s;
    }
}

// ---------------------------------------------------------------------------
// rowptr scan
// ---------------------------------------------------------------------------

#define SCAN_CHUNK 2048

__global__ void k_scan1(const int* __restrict__ counts, int N, int* __restrict__ bsum) {
    __shared__ int sdata[256];
    int b = blockIdx.x, t = threadIdx.x;
    int base = b * SCAN_CHUNK;
    int sum = 0;
    for (int i = t; i < SCAN_CHUNK; i += 256) {
        int idx = base + i;
        sum += (idx < N) ? counts[idx] : 0;
    }
    sdata[t] = sum;
    __syncthreads();
    for (int off = 128; off; off >>= 1) {
        if (t < off) sdata[t] += sdata[t + off];
        __syncthreads();
    }
    if (t == 0) bsum[b] = sdata[0];
}

__global__ void k_scan2(int* __restrict__ bsum, int nb, int E, int* __restrict__ rowptr, int N) {
    if (blockIdx.x == 0 && threadIdx.x == 0) {
        int run = 0;
        for (int i = 0; i < nb; i++) { int v = bsum[i]; bsum[i] = run; run += v; }
        rowptr[N] = E;
    }
}

__global__ void k_scan3(const int* __restrict__ counts, int N,
                        const int* __restrict__ bsum, int* __restrict__ rowptr) {
    __shared__ int sdata[256];
    int b = blockIdx.x, t = threadIdx.x;
    int base = b * SCAN_CHUNK;
    int vals[8];
    int local = 0;
    #pragma unroll
    for (int i = 0; i < 8; i++) {
        int idx = base + t * 8 + i;
        vals[i] = (idx < N) ? counts[idx] : 0;
        local += vals[i];
    }
    sdata[t] = local;
    __syncthreads();
    for (int off = 1; off < 256; off <<= 1) {
        int y = 0;
        if (t >= off) y = sdata[t - off];
        __syncthreads();
        sdata[t] += y;
        __syncthreads();
    }
    int excl = (t == 0) ? 0 : sdata[t - 1];
    int run = bsum[b] + excl;
    #pragma unroll
    for (int i = 0; i < 8; i++) {
        int idx = base + t * 8 + i;
        if (idx < N) rowptr[idx] = run;
        run += vals[i];
    }
}

// ---------------------------------------------------------------------------
// Weight pre-transpose + f16 conversion: W [K][N] f32 -> Wt [N][K] f16
// ---------------------------------------------------------------------------

__global__ void k_w1t(const float* __restrict__ W, _Float16* __restrict__ Wt) {
    int i = blockIdx.x * 256 + threadIdx.x;          // over 512*256
    int k = i >> 8, n = i & 255;
    Wt[(size_t)n * 512 + k] = (_Float16)W[i];
}

__global__ void k_w2t(const float* __restrict__ W, _Float16* __restrict__ Wt) {
    int i = blockIdx.x * 256 + threadIdx.x;          // over 256*64
    int k = i >> 6, n = i & 63;
    Wt[(size_t)n * 256 + k] = (_Float16)W[i];
}

// ---------------------------------------------------------------------------
// MLP layer 1 (BARRIER-FREE single-wave pipeline): hmid = relu(x @ W1 + b1)
// r16 lesson: occupancy 61% did NOT raise BW -- every schedule with a
// block-wide s_barrier per K-step convoys all waves onto the slowest DMA
// (MfmaUtil=VALUBusy=6% while 61% occupied = lockstep stalls). This variant
// has NO barriers: 1 wave per block, wave tile 32 rows x 256 cols (x read
// once), wave-PRIVATE 3x4KB LDS staging, counted vmcnt only. ~12 independent
// waves/CU free-run their own pipelines -> stalls overlap by construction.
// Per iter: asm vmcnt(4) [tile ks is older than the newest 4 loads ->
// guaranteed drained; newest stage stays in flight], 16 B loads (L2-hot),
// stage ks+2 -> buf (ks+2)%3 (disjoint mod 3 from read buffer), 32 MFMA.
// acc[2][16]=128 AGPR + b[16]=64 VGPR ~ 220 regs, fits (64,2)'s 256 budget.
// ---------------------------------------------------------------------------

__global__ __launch_bounds__(64, 2) void k_mlp1(
    const float* __restrict__ A, const _Float16* __restrict__ Bt,
    const float* __restrict__ bias, _Float16* __restrict__ C, int M)
{
    __shared__ float lds[3][32 * 32];    // 3 x 4KB, wave-private (1 wave/block)

    int lane = threadIdx.x;              // 0..63
    int bm   = blockIdx.x * 32;
    int mrow = lane & 15;
    int kg   = lane >> 4;                // 0..3

    // staging: k-tile = 32 rows x 32 f32 = 256 chunks of 16B; chunk q*64+lane:
    // r = q*8 + (lane>>3), c = lane&7; src chunk = c ^ (r&7) = (lane&7)^(lane>>3)
    int sr = lane >> 3;                  // 0..7, + 8*q
    int sc = (lane & 7) ^ sr;
    const float* gsrc[4];
    #pragma unroll
    for (int q = 0; q < 4; q++) {
        int gr = bm + q * 8 + sr;
        if (gr >= M) gr = M - 1;         // clamp: no OOB reads, rows guarded at C-write
        gsrc[q] = A + (size_t)gr * 512 + sc * 4;
    }

    #define STAGE(buf, ks)                                                       \
        {                                                                        \
            _Pragma("unroll")                                                    \
            for (int q = 0; q < 4; q++) {                                        \
                __builtin_amdgcn_global_load_lds(                                \
                    (const __attribute__((address_space(1))) void*)(gsrc[q] + (ks) * 32), \
                    (__attribute__((address_space(3))) void*)((char*)&lds[buf][0] + q * 1024 + lane * 16), \
                    16, 0, 0);                                                   \
            }                                                                    \
        }

    f32x4 acc[2][16] = {};

    // read-side swizzle: chunks (2kg)^(r&7), (2kg+1)^(r&7) of row r
    int rbase[2], p0[2], p1[2];
    #pragma unroll
    for (int mi = 0; mi < 2; mi++) {
        int r = mi * 16 + mrow;
        rbase[mi] = r * 32;
        p0[mi] = ((2 * kg) ^ (r & 7)) * 4;
        p1[mi] = ((2 * kg + 1) ^ (r & 7)) * 4;
    }

    // prologue: 2 stages in flight
    STAGE(0, 0);
    STAGE(1, 1);

    #pragma unroll
    for (int ks = 0; ks < 16; ks++) {
        // S_ks was issued >= 20 loads ago (iter ks-1 had 16 B + 4 stage) ->
        // vmcnt(4) guarantees it drained while the newest stage stays in flight
        asm volatile("s_waitcnt vmcnt(4)" ::: "memory");

        // B fragments (all 16 col-tiles) -- issued BEFORE the stage so the
        // compiler's pre-MFMA b-wait leaves the newest stage outstanding
        half8 b[16];
        #pragma unroll
        for (int ni = 0; ni < 16; ni++) {
            int n = ni * 16 + mrow;
            b[ni] = *(const half8*)(Bt + (size_t)n * 512 + ks * 32 + kg * 8);
        }

        if (ks < 14) STAGE((ks + 2) % 3, ks + 2);

        const float* lbuf = &lds[ks % 3][0];
        half8 a[2];
        #pragma unroll
        for (int mi = 0; mi < 2; mi++) {
            f32x4 lo = *(const f32x4*)&lbuf[rbase[mi] + p0[mi]];
            f32x4 hi = *(const f32x4*)&lbuf[rbase[mi] + p1[mi]];
            a[mi][0] = (_Float16)lo[0]; a[mi][1] = (_Float16)lo[1];
            a[mi][2] = (_Float16)lo[2]; a[mi][3] = (_Float16)lo[3];
            a[mi][4] = (_Float16)hi[0]; a[mi][5] = (_Float16)hi[1];
            a[mi][6] = (_Float16)hi[2]; a[mi][7] = (_Float16)hi[3];
        }

        #pragma unroll
        for (int mi = 0; mi < 2; mi++)
            #pragma unroll
            for (int ni = 0; ni < 16; ni++)
                acc[mi][ni] = __builtin_amdgcn_mfma_f32_16x16x32_f16(
                    a[mi], b[ni], acc[mi][ni], 0, 0, 0);
    }
    #undef STAGE

    #pragma unroll
    for (int mi = 0; mi < 2; mi++) {
        #pragma unroll
        for (int ni = 0; ni < 16; ni++) {
            int n = ni * 16 + mrow;
            float bv = bias[n];
            #pragma unroll
            for (int rg = 0; rg < 4; rg++) {
                int row = bm + mi * 16 + kg * 4 + rg;
                if (row < M) {
                    float v = acc[mi][ni][rg] + bv;
                    C[(size_t)row * 256 + n] = (_Float16)fmaxf(v, 0.f);
                }
            }
        }
    }
}

// ---------------------------------------------------------------------------
// MLP layer 2: h[M][64] f16 = hmid[M][256] f16 @ W2 + b2; also y0 = dinv*h
// ---------------------------------------------------------------------------

__global__ __launch_bounds__(256) void k_mlp2(
    const _Float16* __restrict__ A, const _Float16* __restrict__ Bt,
    const float* __restrict__ bias, const float* __restrict__ dinv,
    _Float16* __restrict__ C, _Float16* __restrict__ Y, int M)
{
    int lane = threadIdx.x & 63;
    int wid  = threadIdx.x >> 6;
    int bm   = blockIdx.x * 256 + wid * 64;
    int mrow = lane & 15;
    int kg   = lane >> 4;
    f32x4 acc[4][4] = {};

    int r[4];
    #pragma unroll
    for (int mi = 0; mi < 4; mi++) {
        int rr = bm + mi * 16 + mrow;
        r[mi] = rr < M ? rr : M - 1;
    }

    for (int k0 = 0; k0 < 256; k0 += 32) {
        int k = k0 + kg * 8;
        half8 a[4], b[4];
        #pragma unroll
        for (int mi = 0; mi < 4; mi++)
            a[mi] = *(const half8*)(A + (size_t)r[mi] * 256 + k);
        #pragma unroll
        for (int ni = 0; ni < 4; ni++) {
            int n = ni * 16 + mrow;
            b[ni] = *(const half8*)(Bt + (size_t)n * 256 + k);
        }
        #pragma unroll
        for (int mi = 0; mi < 4; mi++)
            #pragma unroll
            for (int ni = 0; ni < 4; ni++)
                acc[mi][ni] = __builtin_amdgcn_mfma_f32_16x16x32_f16(
                    a[mi], b[ni], acc[mi][ni], 0, 0, 0);
    }

    #pragma unroll
    for (int mi = 0; mi < 4; mi++) {
        #pragma unroll
        for (int ni = 0; ni < 4; ni++) {
            int n = ni * 16 + mrow;
            float bv = bias[n];
            #pragma unroll
            for (int rg = 0; rg < 4; rg++) {
                int row = bm + mi * 16 + kg * 4 + rg;
                if (row < M) {
                    float v = acc[mi][ni][rg] + bv;
                    C[(size_t)row * 64 + n] = (_Float16)v;
                    Y[(size_t)row * 64 + n] = (_Float16)(v * dinv[row]);
                }
            }
        }
    }
}

// ---------------------------------------------------------------------------
// APPNP propagation on scaled state y = dinv * out (weightless gathers).
// One wave per dst node; 8 lanes per edge (16B -> one 128B line per edge).
// Single MASKED 32-edge pass per iteration (clamped index + 0/1 weight).
// Last iteration fuses log_softmax and writes f32 d_out.
// [r13 lesson: channel-quartering regressed 3.5x; full-row 128B/edge at
//  ~7.7 TB/s effective is the right shape.]
// ---------------------------------------------------------------------------

template <bool LAST>
__global__ __launch_bounds__(256) void k_prop(
    const int* __restrict__ rowptr, const int* __restrict__ csr_src,
    const float* __restrict__ dinv, const _Float16* __restrict__ h,
    const _Float16* __restrict__ ycur, _Float16* __restrict__ ynxt,
    float* __restrict__ out, int N)
{
    int node = blockIdx.x * 4 + (threadIdx.x >> 6);
    if (node >= N) return;
    int lane = threadIdx.x & 63;
    int g  = lane >> 3;       // edge slot 0..7
    int cg = lane & 7;        // channel group: channels [8*cg, 8*cg+8)

    int beg = rowptr[node], end = rowptr[node + 1];
    float dn = dinv[node];
    half8 ys = *(const half8*)(ycur + ((size_t)node << 6) + cg * 8);
    half8 hv = *(const half8*)(h    + ((size_t)node << 6) + cg * 8);

    float acc[8] = {};
    for (int e = beg + g; e < end; e += 32) {
        int i1 = e + 8, i2 = e + 16, i3 = e + 24;
        float p1 = (i1 < end) ? 1.f : 0.f;
        float p2 = (i2 < end) ? 1.f : 0.f;
        float p3 = (i3 < end) ? 1.f : 0.f;
        int s0 = csr_src[e];
        int s1 = csr_src[(i1 < end) ? i1 : e];
        int s2 = csr_src[(i2 < end) ? i2 : e];
        int s3 = csr_src[(i3 < end) ? i3 : e];
        half8 v0 = *(const half8*)(ycur + ((size_t)s0 << 6) + cg * 8);
        half8 v1 = *(const half8*)(ycur + ((size_t)s1 << 6) + cg * 8);
        half8 v2 = *(const half8*)(ycur + ((size_t)s2 << 6) + cg * 8);
        half8 v3 = *(const half8*)(ycur + ((size_t)s3 << 6) + cg * 8);
        #pragma unroll
        for (int c = 0; c < 8; c++)
            acc[c] += ((float)v0[c] + p1 * (float)v1[c])
                    + (p2 * (float)v2[c] + p3 * (float)v3[c]);
    }

    #pragma unroll
    for (int c = 0; c < 8; c++) {
        float a = acc[c];
        a += __shfl_xor(a, 8);
        a += __shfl_xor(a, 16);
        a += __shfl_xor(a, 32);
        acc[c] = a;
    }

    float o[8];
    #pragma unroll
    for (int c = 0; c < 8; c++)
        o[c] = (1.0f - ALPHA) * dn * (acc[c] + (float)ys[c]) + ALPHA * (float)hv[c];

    if (!LAST) {
        if (g == 0) {
            half8 w;
            #pragma unroll
            for (int c = 0; c < 8; c++) w[c] = (_Float16)(dn * o[c]);
            *(half8*)(ynxt + ((size_t)node << 6) + cg * 8) = w;
        }
    } else {
        float m = o[0];
        #pragma unroll
        for (int c = 1; c < 8; c++) m = fmaxf(m, o[c]);
        m = fmaxf(m, __shfl_xor(m, 1));
        m = fmaxf(m, __shfl_xor(m, 2));
        m = fmaxf(m, __shfl_xor(m, 4));
        float s = 0.f;
        #pragma unroll
        for (int c = 0; c < 8; c++) s += __expf(o[c] - m);
        s += __shfl_xor(s, 1);
        s += __shfl_xor(s, 2);
        s += __shfl_xor(s, 4);
        float ls = m + logf(s);
        if (g == 0) {
            f32x4 w0, w1;
            #pragma unroll
            for (int c = 0; c < 4; c++) { w0[c] = o[c] - ls; w1[c] = o[c + 4] - ls; }
            float* p = out + ((size_t)node << 6) + cg * 8;
            *(f32x4*)p = w0;
            *(f32x4*)(p + 4) = w1;
        }
    }
}

// ---------------------------------------------------------------------------
// Launch
// ---------------------------------------------------------------------------

extern "C" void kernel_launch(void* const* d_in, const int* in_sizes, int n_in,
                              void* d_out, int out_size, void* d_ws, size_t ws_size,
                              hipStream_t stream) {
    const float* x  = (const float*)d_in[0];
    const int*   ei = (const int*)d_in[1];
    const float* W1 = (const float*)d_in[2];
    const float* b1 = (const float*)d_in[3];
    const float* W2 = (const float*)d_in[4];
    const float* b2 = (const float*)d_in[5];

    const int N = in_sizes[0] / C_IN;
    const int E = in_sizes[1] / 2;
    const int* src = ei;
    const int* dst = ei + E;

    char* ws = (char*)d_ws;
    size_t off = 0;
    auto alloc = [&](size_t bytes) -> void* {
        void* p = ws + off;
        off += (bytes + 255) & ~(size_t)255;
        return p;
    };

    int nb   = (N + SCAN_CHUNK - 1) / SCAN_CHUNK;
    int nbkt = (N + BKT_NODES - 1) / BKT_NODES;      // 196 for N=100000 (<=256 req'd)

    int*       counts  = (int*)      alloc((size_t)4 * N);
    int*       rowptr  = (int*)      alloc((size_t)4 * (N + 1));
    float*     dinv    = (float*)    alloc((size_t)4 * N);
    int*       bsum    = (int*)      alloc((size_t)4 * (nb + 1));
    int*       bcursor = (int*)      alloc((size_t)4 * nbkt);
    int*       csr_src = (int*)      alloc((size_t)4 * E);
    _Float16*  W1t     = (_Float16*) alloc((size_t)2 * C_IN * C_HID);
    _Float16*  W2t     = (_Float16*) alloc((size_t)2 * C_HID * C_OUT);
    _Float16*  hmid    = (_Float16*) alloc((size_t)2 * N * C_HID);   // 51.2 MB
    _Float16*  h       = (_Float16*) alloc((size_t)2 * N * C_OUT);
    _Float16*  ybuf0   = (_Float16*) alloc((size_t)2 * N * C_OUT);
    _Float16*  ybuf1   = (_Float16*) alloc((size_t)2 * N * C_OUT);
    _Float16*  ybuf2   = (_Float16*) alloc((size_t)2 * N * C_OUT);

    // bedges (nbkt*BCAP*8B = 38.5 MB) aliases hmid (51.2 MB): all bucket
    // passes complete (in-stream) before k_mlp1 writes hmid.
    long long* bedges = (long long*)hmid;

    // --- CSR build: bucket -> count(+dinv) -> scan -> scatter ---
    hipMemsetAsync(bcursor, 0, (size_t)4 * nbkt, stream);
    k_bucketA<<<(E + EPB - 1) / EPB, 256, 0, stream>>>(src, dst, E, bcursor, bedges, nbkt);
    k_bcount<<<nbkt, 256, 0, stream>>>(bcursor, bedges, counts, dinv, N);
    k_scan1<<<nb, 256, 0, stream>>>(counts, N, bsum);
    k_scan2<<<1, 64, 0, stream>>>(bsum, nb, E, rowptr, N);
    k_scan3<<<nb, 256, 0, stream>>>(counts, N, bsum, rowptr);
    k_bscatter<<<nbkt, 256, 0, stream>>>(bcursor, bedges, rowptr, csr_src, N);

    // --- weight conversion + MLP (f16 MFMA) ---
    k_w1t<<<(C_IN * C_HID) / 256, 256, 0, stream>>>(W1, W1t);
    k_w2t<<<(C_HID * C_OUT) / 256, 256, 0, stream>>>(W2, W2t);
    k_mlp1<<<(N + 31) / 32, 64, 0, stream>>>(x, W1t, b1, hmid, N);
    k_mlp2<<<(N + 255) / 256, 256, 0, stream>>>(hmid, W2t, b2, dinv, h, ybuf0, N);

    // --- propagation on y; last iteration fuses log_softmax ---
    int pgrid = (N + 3) / 4;
    _Float16* ycur = ybuf0;
    for (int it = 0; it < K_STEPS - 1; ++it) {
        _Float16* ynxt = (it & 1) ? ybuf2 : ybuf1;
        k_prop<false><<<pgrid, 256, 0, stream>>>(rowptr, csr_src, dinv, h, ycur, ynxt, nullptr, N);
        ycur = ynxt;
    }
    k_prop<true><<<pgrid, 256, 0, stream>>>(rowptr, csr_src, dinv, h, ycur, nullptr, (float*)d_out, N);
}

// Round 18
// 758.842 us; speedup vs baseline: 1.1136x; 1.1136x over previous
//
#include <hip/hip_runtime.h>
#include <hip/hip_bf16.h>

#define C_IN  512
#define C_HID 256
#define C_OUT 64
#define K_STEPS 10
#define ALPHA 0.1f

#define BKT_SHIFT 9          // 512 nodes per bucket
#define BKT_NODES 512
#define BCAP 24576           // per-bucket edge capacity (mean 16384 -> huge margin)
#define EPB 4096             // edges per block in pass A (16 per thread)

typedef _Float16 half8 __attribute__((ext_vector_type(8)));
typedef float f32x4 __attribute__((ext_vector_type(4)));

// ---------------------------------------------------------------------------
// CSR build via two-level counting sort (write-locality-friendly)
// ---------------------------------------------------------------------------

__global__ __launch_bounds__(256) void k_bucketA(
    const int* __restrict__ src, const int* __restrict__ dst, int E,
    int* __restrict__ bcursor, long long* __restrict__ bedges, int nbkt)
{
    __shared__ int lcount[256];
    __shared__ int lbase[256];
    int t = threadIdx.x;
    int base = blockIdx.x * EPB;
    for (int i = t; i < nbkt; i += 256) lcount[i] = 0;
    __syncthreads();

    int       mybkt[16];
    int       myoff[16];
    long long mypk[16];
    #pragma unroll
    for (int j = 0; j < 16; j++) {
        int e = base + j * 256 + t;          // coalesced
        if (e < E) {
            int s = src[e], d = dst[e];
            int b = d >> BKT_SHIFT;
            mybkt[j] = b;
            mypk[j]  = ((long long)d << 32) | (unsigned int)s;
            myoff[j] = atomicAdd(&lcount[b], 1);
        } else {
            mybkt[j] = -1;
        }
    }
    __syncthreads();
    for (int i = t; i < nbkt; i += 256)
        lbase[i] = lcount[i] ? atomicAdd(&bcursor[i], lcount[i]) : 0;
    __syncthreads();
    #pragma unroll
    for (int j = 0; j < 16; j++) {
        if (mybkt[j] >= 0) {
            int p = lbase[mybkt[j]] + myoff[j];
            bedges[(size_t)mybkt[j] * BCAP + p] = mypk[j];
        }
    }
}

// tiny: exclusive prefix over per-bucket counts -> bktbase; also rowptr[N]=E
__global__ void k_bscan(const int* __restrict__ bcursor, int nbkt,
                        int* __restrict__ bktbase, int* __restrict__ rowptr,
                        int N, int E)
{
    if (blockIdx.x == 0 && threadIdx.x == 0) {
        int run = 0;
        for (int i = 0; i < nbkt; i++) { bktbase[i] = run; run += bcursor[i]; }
        rowptr[N] = E;
    }
}

// Fused per-bucket finalize: histogram -> local scan -> rowptr + dinv ->
// scatter csr_src. Replaces k_bcount + k_scan1/3 + k_bscatter (r17 config).
__global__ __launch_bounds__(256) void k_bfin(
    const int* __restrict__ bcursor, const int* __restrict__ bktbase,
    const long long* __restrict__ bedges, int* __restrict__ rowptr,
    float* __restrict__ dinv, int* __restrict__ csr_src, int N)
{
    __shared__ int lcnt[BKT_NODES];
    __shared__ int lofs[BKT_NODES];
    __shared__ int sdata[256];
    int b = blockIdx.x, t = threadIdx.x;
    int nodebase = b << BKT_SHIFT;

    lcnt[2 * t] = 0; lcnt[2 * t + 1] = 0;
    __syncthreads();

    int cnt = bcursor[b];
    const long long* be = bedges + (size_t)b * BCAP;
    for (int i = t; i < cnt; i += 256) {
        int d = (int)(be[i] >> 32);
        atomicAdd(&lcnt[d - nodebase], 1);
    }
    __syncthreads();

    // local exclusive scan over 512 entries (pair per thread + Hillis-Steele)
    int v0 = lcnt[2 * t], v1 = lcnt[2 * t + 1];
    int psum = v0 + v1;
    sdata[t] = psum;
    __syncthreads();
    for (int off = 1; off < 256; off <<= 1) {
        int y = 0;
        if (t >= off) y = sdata[t - off];
        __syncthreads();
        sdata[t] += y;
        __syncthreads();
    }
    int excl = sdata[t] - psum;                   // exclusive over pairs
    int base = bktbase[b];
    lofs[2 * t]     = base + excl;
    lofs[2 * t + 1] = base + excl + v0;
    __syncthreads();

    // rowptr + dinv (counts array eliminated)
    #pragma unroll
    for (int j = 0; j < 2; j++) {
        int i = 2 * t + j;
        int node = nodebase + i;
        if (node < N) {
            rowptr[node] = lofs[i];
            dinv[node] = 1.0f / sqrtf((float)(lcnt[i] + 1));
        }
    }
    __syncthreads();

    // scatter into this bucket's contiguous csr window
    for (int i = t; i < cnt; i += 256) {
        long long pk = be[i];
        int d = (int)(pk >> 32);
        int s = (int)pk;
        int p = atomicAdd(&lofs[d - nodebase], 1);
        csr_src[p] = s;
    }
}

// ---------------------------------------------------------------------------
// Weight pre-transpose + f16 conversion (both weights, one launch)
// ---------------------------------------------------------------------------

__global__ void k_wt(const float* __restrict__ W1, const float* __restrict__ W2,
                     _Float16* __restrict__ W1t, _Float16* __restrict__ W2t)
{
    int i = blockIdx.x * 256 + threadIdx.x;
    if (i < C_IN * C_HID) {                       // 131072
        int k = i >> 8, n = i & 255;
        W1t[(size_t)n * 512 + k] = (_Float16)W1[i];
    } else {
        int j = i - C_IN * C_HID;                 // over 256*64
        if (j < C_HID * C_OUT) {
            int k = j >> 6, n = j & 63;
            W2t[(size_t)n * 256 + k] = (_Float16)W2[j];
        }
    }
}

// ---------------------------------------------------------------------------
// MLP layer 1 (r9-exact, proven 120us): hmid = relu(x @ W1 + b1)
// BM=128, BN=256 (x read ONCE), BK=32, 16 K-steps. 2x16KB LDS dbuf via
// global_load_lds width=16, XOR-swizzled source / linear LDS dest, swizzled
// ds_read_b128. 4 waves 2x2, each 64 rows x 128 cols (acc 4x8 = 128 AGPR).
// launch_bounds MUST stay (256,2): (256,3) spilled accumulators (r10);
// all 8 alternative schedules r10-r17 landed 120-210us -- this is the best.
// ---------------------------------------------------------------------------

__global__ __launch_bounds__(256, 2) void k_mlp1(
    const float* __restrict__ A, const _Float16* __restrict__ Bt,
    const float* __restrict__ bias, _Float16* __restrict__ C, int M)
{
    __shared__ float lds[2][128 * 32];   // 2 x 16KB

    int t    = threadIdx.x;
    int lane = t & 63;
    int wid  = t >> 6;
    int bm   = blockIdx.x * 128;
    int wr   = wid >> 1;                 // wave row (0..1) -> rows 64*wr
    int wc   = wid & 1;                  // wave col (0..1) -> cols 128*wc
    int mrow = lane & 15;
    int kg   = lane >> 4;                // 0..3

    // staging geometry: LDS chunk (q*256 + wid*64 + lane) <- global chunk
    // row r = q*32+wid*8+(lane>>3), pos c = lane&7, src chunk = c ^ (r&7)
    int srow = wid * 8 + (lane >> 3);    // + 32*q
    int cgs  = (lane & 7) ^ (lane >> 3);

    const float* gsrc[4];
    #pragma unroll
    for (int q = 0; q < 4; q++) {
        int gr = bm + q * 32 + srow;
        if (gr >= M) gr = M - 1;         // clamp: no OOB reads, rows discarded at C-write
        gsrc[q] = A + (size_t)gr * 512 + cgs * 4;
    }

    #define STAGE(buf, ks)                                                       \
        {                                                                        \
            _Pragma("unroll")                                                    \
            for (int q = 0; q < 4; q++) {                                        \
                __builtin_amdgcn_global_load_lds(                                \
                    (const __attribute__((address_space(1))) void*)(gsrc[q] + (ks) * 32), \
                    (__attribute__((address_space(3))) void*)((char*)&lds[buf][0] + q * 4096 + wid * 1024), \
                    16, 0, 0);                                                   \
            }                                                                    \
        }

    f32x4 acc[4][8] = {};

    // read-side swizzle: row_local&7 == lane&7 for all mi (offsets mult of 8)
    int m7 = lane & 7;
    int rbase[4];
    #pragma unroll
    for (int mi = 0; mi < 4; mi++)
        rbase[mi] = (wr * 64 + mi * 16 + mrow) * 32;
    int p0 = ((2 * kg) ^ m7) * 4;
    int p1 = ((2 * kg + 1) ^ m7) * 4;

    STAGE(0, 0);
    __syncthreads();

    int cur = 0;
    for (int ks = 0; ks < 16; ks++) {
        if (ks < 15) STAGE(cur ^ 1, ks + 1);

        // B fragments direct from L2-resident W1t
        half8 b[8];
        #pragma unroll
        for (int ni = 0; ni < 8; ni++) {
            int n = wc * 128 + ni * 16 + mrow;
            b[ni] = *(const half8*)(Bt + (size_t)n * 512 + ks * 32 + kg * 8);
        }

        // A fragments from LDS (swizzled), convert f32 -> f16
        half8 a[4];
        #pragma unroll
        for (int mi = 0; mi < 4; mi++) {
            f32x4 lo = *(const f32x4*)&lds[cur][rbase[mi] + p0];
            f32x4 hi = *(const f32x4*)&lds[cur][rbase[mi] + p1];
            a[mi][0] = (_Float16)lo[0]; a[mi][1] = (_Float16)lo[1];
            a[mi][2] = (_Float16)lo[2]; a[mi][3] = (_Float16)lo[3];
            a[mi][4] = (_Float16)hi[0]; a[mi][5] = (_Float16)hi[1];
            a[mi][6] = (_Float16)hi[2]; a[mi][7] = (_Float16)hi[3];
        }

        #pragma unroll
        for (int mi = 0; mi < 4; mi++)
            #pragma unroll
            for (int ni = 0; ni < 8; ni++)
                acc[mi][ni] = __builtin_amdgcn_mfma_f32_16x16x32_f16(
                    a[mi], b[ni], acc[mi][ni], 0, 0, 0);

        __syncthreads();   // drains stage(ks+1) + guards buffer reuse
        cur ^= 1;
    }
    #undef STAGE

    #pragma unroll
    for (int mi = 0; mi < 4; mi++) {
        #pragma unroll
        for (int ni = 0; ni < 8; ni++) {
            int n = wc * 128 + ni * 16 + mrow;
            float bv = bias[n];
            #pragma unroll
            for (int rg = 0; rg < 4; rg++) {
                int row = bm + wr * 64 + mi * 16 + kg * 4 + rg;
                if (row < M) {
                    float v = acc[mi][ni][rg] + bv;
                    C[(size_t)row * 256 + n] = (_Float16)fmaxf(v, 0.f);
                }
            }
        }
    }
}

// ---------------------------------------------------------------------------
// MLP layer 2: h[M][64] f16 = hmid[M][256] f16 @ W2 + b2; also y0 = dinv*h
// ---------------------------------------------------------------------------

__global__ __launch_bounds__(256) void k_mlp2(
    const _Float16* __restrict__ A, const _Float16* __restrict__ Bt,
    const float* __restrict__ bias, const float* __restrict__ dinv,
    _Float16* __restrict__ C, _Float16* __restrict__ Y, int M)
{
    int lane = threadIdx.x & 63;
    int wid  = threadIdx.x >> 6;
    int bm   = blockIdx.x * 256 + wid * 64;
    int mrow = lane & 15;
    int kg   = lane >> 4;
    f32x4 acc[4][4] = {};

    int r[4];
    #pragma unroll
    for (int mi = 0; mi < 4; mi++) {
        int rr = bm + mi * 16 + mrow;
        r[mi] = rr < M ? rr : M - 1;
    }

    for (int k0 = 0; k0 < 256; k0 += 32) {
        int k = k0 + kg * 8;
        half8 a[4], b[4];
        #pragma unroll
        for (int mi = 0; mi < 4; mi++)
            a[mi] = *(const half8*)(A + (size_t)r[mi] * 256 + k);
        #pragma unroll
        for (int ni = 0; ni < 4; ni++) {
            int n = ni * 16 + mrow;
            b[ni] = *(const half8*)(Bt + (size_t)n * 256 + k);
        }
        #pragma unroll
        for (int mi = 0; mi < 4; mi++)
            #pragma unroll
            for (int ni = 0; ni < 4; ni++)
                acc[mi][ni] = __builtin_amdgcn_mfma_f32_16x16x32_f16(
                    a[mi], b[ni], acc[mi][ni], 0, 0, 0);
    }

    #pragma unroll
    for (int mi = 0; mi < 4; mi++) {
        #pragma unroll
        for (int ni = 0; ni < 4; ni++) {
            int n = ni * 16 + mrow;
            float bv = bias[n];
            #pragma unroll
            for (int rg = 0; rg < 4; rg++) {
                int row = bm + mi * 16 + kg * 4 + rg;
                if (row < M) {
                    float v = acc[mi][ni][rg] + bv;
                    C[(size_t)row * 64 + n] = (_Float16)v;
                    Y[(size_t)row * 64 + n] = (_Float16)(v * dinv[row]);
                }
            }
        }
    }
}

// ---------------------------------------------------------------------------
// APPNP propagation on scaled state y = dinv * out (weightless gathers).
// One wave per dst node; 8 lanes per edge (16B -> one 128B line per edge).
// Single MASKED 32-edge pass per iteration (clamped index + 0/1 weight).
// Last iteration fuses log_softmax and writes f32 d_out.
// [r13 lesson: channel-quartering regressed 3.5x; full-row 128B/edge at
//  ~7.7 TB/s effective is the right shape.]
// ---------------------------------------------------------------------------

template <bool LAST>
__global__ __launch_bounds__(256) void k_prop(
    const int* __restrict__ rowptr, const int* __restrict__ csr_src,
    const float* __restrict__ dinv, const _Float16* __restrict__ h,
    const _Float16* __restrict__ ycur, _Float16* __restrict__ ynxt,
    float* __restrict__ out, int N)
{
    int node = blockIdx.x * 4 + (threadIdx.x >> 6);
    if (node >= N) return;
    int lane = threadIdx.x & 63;
    int g  = lane >> 3;       // edge slot 0..7
    int cg = lane & 7;        // channel group: channels [8*cg, 8*cg+8)

    int beg = rowptr[node], end = rowptr[node + 1];
    float dn = dinv[node];
    half8 ys = *(const half8*)(ycur + ((size_t)node << 6) + cg * 8);
    half8 hv = *(const half8*)(h    + ((size_t)node << 6) + cg * 8);

    float acc[8] = {};
    for (int e = beg + g; e < end; e += 32) {
        int i1 = e + 8, i2 = e + 16, i3 = e + 24;
        float p1 = (i1 < end) ? 1.f : 0.f;
        float p2 = (i2 < end) ? 1.f : 0.f;
        float p3 = (i3 < end) ? 1.f : 0.f;
        int s0 = csr_src[e];
        int s1 = csr_src[(i1 < end) ? i1 : e];
        int s2 = csr_src[(i2 < end) ? i2 : e];
        int s3 = csr_src[(i3 < end) ? i3 : e];
        half8 v0 = *(const half8*)(ycur + ((size_t)s0 << 6) + cg * 8);
        half8 v1 = *(const half8*)(ycur + ((size_t)s1 << 6) + cg * 8);
        half8 v2 = *(const half8*)(ycur + ((size_t)s2 << 6) + cg * 8);
        half8 v3 = *(const half8*)(ycur + ((size_t)s3 << 6) + cg * 8);
        #pragma unroll
        for (int c = 0; c < 8; c++)
            acc[c] += ((float)v0[c] + p1 * (float)v1[c])
                    + (p2 * (float)v2[c] + p3 * (float)v3[c]);
    }

    #pragma unroll
    for (int c = 0; c < 8; c++) {
        float a = acc[c];
        a += __shfl_xor(a, 8);
        a += __shfl_xor(a, 16);
        a += __shfl_xor(a, 32);
        acc[c] = a;
    }

    float o[8];
    #pragma unroll
    for (int c = 0; c < 8; c++)
        o[c] = (1.0f - ALPHA) * dn * (acc[c] + (float)ys[c]) + ALPHA * (float)hv[c];

    if (!LAST) {
        if (g == 0) {
            half8 w;
            #pragma unroll
            for (int c = 0; c < 8; c++) w[c] = (_Float16)(dn * o[c]);
            *(half8*)(ynxt + ((size_t)node << 6) + cg * 8) = w;
        }
    } else {
        float m = o[0];
        #pragma unroll
        for (int c = 1; c < 8; c++) m = fmaxf(m, o[c]);
        m = fmaxf(m, __shfl_xor(m, 1));
        m = fmaxf(m, __shfl_xor(m, 2));
        m = fmaxf(m, __shfl_xor(m, 4));
        float s = 0.f;
        #pragma unroll
        for (int c = 0; c < 8; c++) s += __expf(o[c] - m);
        s += __shfl_xor(s, 1);
        s += __shfl_xor(s, 2);
        s += __shfl_xor(s, 4);
        float ls = m + logf(s);
        if (g == 0) {
            f32x4 w0, w1;
            #pragma unroll
            for (int c = 0; c < 4; c++) { w0[c] = o[c] - ls; w1[c] = o[c + 4] - ls; }
            float* p = out + ((size_t)node << 6) + cg * 8;
            *(f32x4*)p = w0;
            *(f32x4*)(p + 4) = w1;
        }
    }
}

// ---------------------------------------------------------------------------
// Launch
// ---------------------------------------------------------------------------

extern "C" void kernel_launch(void* const* d_in, const int* in_sizes, int n_in,
                              void* d_out, int out_size, void* d_ws, size_t ws_size,
                              hipStream_t stream) {
    const float* x  = (const float*)d_in[0];
    const int*   ei = (const int*)d_in[1];
    const float* W1 = (const float*)d_in[2];
    const float* b1 = (const float*)d_in[3];
    const float* W2 = (const float*)d_in[4];
    const float* b2 = (const float*)d_in[5];

    const int N = in_sizes[0] / C_IN;
    const int E = in_sizes[1] / 2;
    const int* src = ei;
    const int* dst = ei + E;

    char* ws = (char*)d_ws;
    size_t off = 0;
    auto alloc = [&](size_t bytes) -> void* {
        void* p = ws + off;
        off += (bytes + 255) & ~(size_t)255;
        return p;
    };

    int nbkt = (N + BKT_NODES - 1) / BKT_NODES;      // 196 for N=100000 (<=256 req'd)

    int*       rowptr  = (int*)      alloc((size_t)4 * (N + 1));
    float*     dinv    = (float*)    alloc((size_t)4 * N);
    int*       bcursor = (int*)      alloc((size_t)4 * nbkt);
    int*       bktbase = (int*)      alloc((size_t)4 * (nbkt + 1));
    int*       csr_src = (int*)      alloc((size_t)4 * E);
    _Float16*  W1t     = (_Float16*) alloc((size_t)2 * C_IN * C_HID);
    _Float16*  W2t     = (_Float16*) alloc((size_t)2 * C_HID * C_OUT);
    _Float16*  hmid    = (_Float16*) alloc((size_t)2 * N * C_HID);   // 51.2 MB
    _Float16*  h       = (_Float16*) alloc((size_t)2 * N * C_OUT);
    _Float16*  ybuf0   = (_Float16*) alloc((size_t)2 * N * C_OUT);
    _Float16*  ybuf1   = (_Float16*) alloc((size_t)2 * N * C_OUT);
    _Float16*  ybuf2   = (_Float16*) alloc((size_t)2 * N * C_OUT);

    // bedges (nbkt*BCAP*8B = 38.5 MB) aliases hmid (51.2 MB): all bucket
    // passes complete (in-stream) before k_mlp1 writes hmid.
    long long* bedges = (long long*)hmid;

    // --- CSR build: bucket -> bucket-prefix -> fused finalize ---
    hipMemsetAsync(bcursor, 0, (size_t)4 * nbkt, stream);
    k_bucketA<<<(E + EPB - 1) / EPB, 256, 0, stream>>>(src, dst, E, bcursor, bedges, nbkt);
    k_bscan<<<1, 64, 0, stream>>>(bcursor, nbkt, bktbase, rowptr, N, E);
    k_bfin<<<nbkt, 256, 0, stream>>>(bcursor, bktbase, bedges, rowptr, dinv, csr_src, N);

    // --- weight conversion + MLP (f16 MFMA) ---
    int wtot = C_IN * C_HID + C_HID * C_OUT;
    k_wt<<<(wtot + 255) / 256, 256, 0, stream>>>(W1, W2, W1t, W2t);
    k_mlp1<<<(N + 127) / 128, 256, 0, stream>>>(x, W1t, b1, hmid, N);
    k_mlp2<<<(N + 255) / 256, 256, 0, stream>>>(hmid, W2t, b2, dinv, h, ybuf0, N);

    // --- propagation on y; last iteration fuses log_softmax ---
    int pgrid = (N + 3) / 4;
    _Float16* ycur = ybuf0;
    for (int it = 0; it < K_STEPS - 1; ++it) {
        _Float16* ynxt = (it & 1) ? ybuf2 : ybuf1;
        k_prop<false><<<pgrid, 256, 0, stream>>>(rowptr, csr_src, dinv, h, ycur, ynxt, nullptr, N);
        ycur = ynxt;
    }
    k_prop<true><<<pgrid, 256, 0, stream>>>(rowptr, csr_src, dinv, h, ycur, nullptr, (float*)d_out, N);
}

// Round 19
// 736.174 us; speedup vs baseline: 1.1479x; 1.0308x over previous
//
#include <hip/hip_runtime.h>
#include <hip/hip_bf16.h>

#define C_IN  512
#define C_HID 256
#define C_OUT 64
#define K_STEPS 10
#define ALPHA 0.1f

#define BKT_SHIFT 9          // 512 nodes per bucket
#define BKT_NODES 512
#define BCAP 24576           // per-bucket edge capacity (mean 16384 -> huge margin)
#define EPB 4096             // edges per block in pass A (16 per thread)

typedef _Float16 half8 __attribute__((ext_vector_type(8)));
typedef float f32x4 __attribute__((ext_vector_type(4)));

// ---------------------------------------------------------------------------
// CSR build via two-level counting sort (write-locality-friendly)
// ---------------------------------------------------------------------------

__global__ __launch_bounds__(256) void k_bucketA(
    const int* __restrict__ src, const int* __restrict__ dst, int E,
    int* __restrict__ bcursor, long long* __restrict__ bedges, int nbkt)
{
    __shared__ int lcount[256];
    __shared__ int lbase[256];
    int t = threadIdx.x;
    int base = blockIdx.x * EPB;
    for (int i = t; i < nbkt; i += 256) lcount[i] = 0;
    __syncthreads();

    int       mybkt[16];
    int       myoff[16];
    long long mypk[16];
    #pragma unroll
    for (int j = 0; j < 16; j++) {
        int e = base + j * 256 + t;          // coalesced
        if (e < E) {
            int s = src[e], d = dst[e];
            int b = d >> BKT_SHIFT;
            mybkt[j] = b;
            mypk[j]  = ((long long)d << 32) | (unsigned int)s;
            myoff[j] = atomicAdd(&lcount[b], 1);
        } else {
            mybkt[j] = -1;
        }
    }
    __syncthreads();
    for (int i = t; i < nbkt; i += 256)
        lbase[i] = lcount[i] ? atomicAdd(&bcursor[i], lcount[i]) : 0;
    __syncthreads();
    #pragma unroll
    for (int j = 0; j < 16; j++) {
        if (mybkt[j] >= 0) {
            int p = lbase[mybkt[j]] + myoff[j];
            bedges[(size_t)mybkt[j] * BCAP + p] = mypk[j];
        }
    }
}

// tiny: exclusive prefix over per-bucket counts -> bktbase; also rowptr[N]=E
__global__ void k_bscan(const int* __restrict__ bcursor, int nbkt,
                        int* __restrict__ bktbase, int* __restrict__ rowptr,
                        int N, int E)
{
    if (blockIdx.x == 0 && threadIdx.x == 0) {
        int run = 0;
        for (int i = 0; i < nbkt; i++) { bktbase[i] = run; run += bcursor[i]; }
        rowptr[N] = E;
    }
}

// Fused per-bucket finalize: histogram -> local scan -> rowptr + dinv ->
// scatter csr_src.
__global__ __launch_bounds__(256) void k_bfin(
    const int* __restrict__ bcursor, const int* __restrict__ bktbase,
    const long long* __restrict__ bedges, int* __restrict__ rowptr,
    float* __restrict__ dinv, int* __restrict__ csr_src, int N)
{
    __shared__ int lcnt[BKT_NODES];
    __shared__ int lofs[BKT_NODES];
    __shared__ int sdata[256];
    int b = blockIdx.x, t = threadIdx.x;
    int nodebase = b << BKT_SHIFT;

    lcnt[2 * t] = 0; lcnt[2 * t + 1] = 0;
    __syncthreads();

    int cnt = bcursor[b];
    const long long* be = bedges + (size_t)b * BCAP;
    for (int i = t; i < cnt; i += 256) {
        int d = (int)(be[i] >> 32);
        atomicAdd(&lcnt[d - nodebase], 1);
    }
    __syncthreads();

    // local exclusive scan over 512 entries (pair per thread + Hillis-Steele)
    int v0 = lcnt[2 * t], v1 = lcnt[2 * t + 1];
    int psum = v0 + v1;
    sdata[t] = psum;
    __syncthreads();
    for (int off = 1; off < 256; off <<= 1) {
        int y = 0;
        if (t >= off) y = sdata[t - off];
        __syncthreads();
        sdata[t] += y;
        __syncthreads();
    }
    int excl = sdata[t] - psum;                   // exclusive over pairs
    int base = bktbase[b];
    lofs[2 * t]     = base + excl;
    lofs[2 * t + 1] = base + excl + v0;
    __syncthreads();

    #pragma unroll
    for (int j = 0; j < 2; j++) {
        int i = 2 * t + j;
        int node = nodebase + i;
        if (node < N) {
            rowptr[node] = lofs[i];
            dinv[node] = 1.0f / sqrtf((float)(lcnt[i] + 1));
        }
    }
    __syncthreads();

    for (int i = t; i < cnt; i += 256) {
        long long pk = be[i];
        int d = (int)(pk >> 32);
        int s = (int)pk;
        int p = atomicAdd(&lofs[d - nodebase], 1);
        csr_src[p] = s;
    }
}

// ---------------------------------------------------------------------------
// Weight pre-transpose + f16 conversion (both weights, one launch)
// ---------------------------------------------------------------------------

__global__ void k_wt(const float* __restrict__ W1, const float* __restrict__ W2,
                     _Float16* __restrict__ W1t, _Float16* __restrict__ W2t)
{
    int i = blockIdx.x * 256 + threadIdx.x;
    if (i < C_IN * C_HID) {                       // 131072
        int k = i >> 8, n = i & 255;
        W1t[(size_t)n * 512 + k] = (_Float16)W1[i];
    } else {
        int j = i - C_IN * C_HID;                 // over 256*64
        if (j < C_HID * C_OUT) {
            int k = j >> 6, n = j & 63;
            W2t[(size_t)n * 256 + k] = (_Float16)W2[j];
        }
    }
}

// ---------------------------------------------------------------------------
// FUSED MLP: h = (relu(x @ W1 + b1)) @ W2 + b2 and y0 = dinv * h, one kernel.
// Phase 1 = r9-exact GEMM1 (proven 120us): BM=128, BN=256, BK=32, 2x16KB
// stage dbuf via global_load_lds w16, XOR-swizzled src / linear LDS dest,
// swizzled ds_read_b128, 4 waves 2x2, acc[4][8]. launch_bounds MUST stay
// (256,2) (r10: min-waves 3 spills the 128-AGPR accumulator).
// Phase 1.5: relu tile -> 64KB chunk-swizzled LDS htile[128][256]
// (chunk' = chunk ^ (row&7); write & read use the SAME formula).
// Phase 2: GEMM2 (K=256) from htile + L2-hot W2t; epilogue writes h + y0.
// hmid buffer ELIMINATED (-102 MB traffic, -1 dispatch). The 32KB stage
// region overlaps htile: stage is dead after the K-loop's final barrier.
// ---------------------------------------------------------------------------

__global__ __launch_bounds__(256, 2) void k_mlp(
    const float* __restrict__ A, const _Float16* __restrict__ Bt,
    const _Float16* __restrict__ W2t, const float* __restrict__ bias1,
    const float* __restrict__ bias2, const float* __restrict__ dinv,
    _Float16* __restrict__ H, _Float16* __restrict__ Y, int M)
{
    extern __shared__ __align__(16) char smem[];          // 64 KB dynamic
    float*    stagef = (float*)smem;                      // [2][4096] f32
    _Float16* htile  = (_Float16*)smem;                   // [128][256] f16 swz

    int t    = threadIdx.x;
    int lane = t & 63;
    int wid  = t >> 6;
    int bm   = blockIdx.x * 128;
    int wr   = wid >> 1;                 // wave row (0..1) -> rows 64*wr
    int wc   = wid & 1;                  // wave col (0..1) -> cols 128*wc
    int mrow = lane & 15;
    int kg   = lane >> 4;                // 0..3

    // staging geometry (r9): LDS chunk (q*256 + wid*64 + lane) <- global chunk
    // row r = q*32+wid*8+(lane>>3), pos c = lane&7, src chunk = c ^ (r&7)
    int srow = wid * 8 + (lane >> 3);    // + 32*q
    int cgs  = (lane & 7) ^ (lane >> 3);

    const float* gsrc[4];
    #pragma unroll
    for (int q = 0; q < 4; q++) {
        int gr = bm + q * 32 + srow;
        if (gr >= M) gr = M - 1;         // clamp: no OOB reads, rows guarded at output
        gsrc[q] = A + (size_t)gr * 512 + cgs * 4;
    }

    #define STAGE(buf, ks)                                                       \
        {                                                                        \
            _Pragma("unroll")                                                    \
            for (int q = 0; q < 4; q++) {                                        \
                __builtin_amdgcn_global_load_lds(                                \
                    (const __attribute__((address_space(1))) void*)(gsrc[q] + (ks) * 32), \
                    (__attribute__((address_space(3))) void*)(smem + (buf) * 16384 + q * 4096 + wid * 1024), \
                    16, 0, 0);                                                   \
            }                                                                    \
        }

    f32x4 acc[4][8] = {};

    // read-side swizzle: row_local&7 == lane&7 for all mi (offsets mult of 8)
    int m7 = lane & 7;
    int rbase[4];
    #pragma unroll
    for (int mi = 0; mi < 4; mi++)
        rbase[mi] = (wr * 64 + mi * 16 + mrow) * 32;
    int p0 = ((2 * kg) ^ m7) * 4;
    int p1 = ((2 * kg + 1) ^ m7) * 4;

    STAGE(0, 0);
    __syncthreads();

    int cur = 0;
    for (int ks = 0; ks < 16; ks++) {
        if (ks < 15) STAGE(cur ^ 1, ks + 1);

        half8 b[8];
        #pragma unroll
        for (int ni = 0; ni < 8; ni++) {
            int n = wc * 128 + ni * 16 + mrow;
            b[ni] = *(const half8*)(Bt + (size_t)n * 512 + ks * 32 + kg * 8);
        }

        half8 a[4];
        #pragma unroll
        for (int mi = 0; mi < 4; mi++) {
            f32x4 lo = *(const f32x4*)&stagef[cur * 4096 + rbase[mi] + p0];
            f32x4 hi = *(const f32x4*)&stagef[cur * 4096 + rbase[mi] + p1];
            a[mi][0] = (_Float16)lo[0]; a[mi][1] = (_Float16)lo[1];
            a[mi][2] = (_Float16)lo[2]; a[mi][3] = (_Float16)lo[3];
            a[mi][4] = (_Float16)hi[0]; a[mi][5] = (_Float16)hi[1];
            a[mi][6] = (_Float16)hi[2]; a[mi][7] = (_Float16)hi[3];
        }

        #pragma unroll
        for (int mi = 0; mi < 4; mi++)
            #pragma unroll
            for (int ni = 0; ni < 8; ni++)
                acc[mi][ni] = __builtin_amdgcn_mfma_f32_16x16x32_f16(
                    a[mi], b[ni], acc[mi][ni], 0, 0, 0);

        __syncthreads();   // drains stage(ks+1) + guards buffer reuse
        cur ^= 1;
    }
    #undef STAGE
    // all stage reads complete chip-wide (final barrier above) -> htile may
    // now overwrite the stage region.

    // --- phase 1.5: relu(acc + b1) -> swizzled htile[row][col] ---
    #pragma unroll
    for (int mi = 0; mi < 4; mi++) {
        #pragma unroll
        for (int ni = 0; ni < 8; ni++) {
            int col = wc * 128 + ni * 16 + mrow;
            float bv = bias1[col];
            int chunk = col >> 3, within = col & 7;
            #pragma unroll
            for (int rg = 0; rg < 4; rg++) {
                int row = wr * 64 + mi * 16 + kg * 4 + rg;   // local 0..127
                float v = fmaxf(acc[mi][ni][rg] + bv, 0.f);
                htile[row * 256 + ((chunk ^ (row & 7)) << 3) + within] = (_Float16)v;
            }
        }
    }
    __syncthreads();

    // --- phase 2: h-tile(128x64) = htile(128x256) @ W2 + b2; y0 = dinv*h ---
    f32x4 acc2[2][4] = {};
    for (int ks = 0; ks < 8; ks++) {
        half8 b2[4];
        #pragma unroll
        for (int ni = 0; ni < 4; ni++) {
            int n = ni * 16 + mrow;
            b2[ni] = *(const half8*)(W2t + (size_t)n * 256 + ks * 32 + kg * 8);
        }
        half8 a2[2];
        #pragma unroll
        for (int mi = 0; mi < 2; mi++) {
            int row = wid * 32 + mi * 16 + mrow;             // local 0..127
            int chunk = ks * 4 + kg;                         // k = chunk*8
            a2[mi] = *(const half8*)&htile[row * 256 + ((chunk ^ (row & 7)) << 3)];
        }
        #pragma unroll
        for (int mi = 0; mi < 2; mi++)
            #pragma unroll
            for (int ni = 0; ni < 4; ni++)
                acc2[mi][ni] = __builtin_amdgcn_mfma_f32_16x16x32_f16(
                    a2[mi], b2[ni], acc2[mi][ni], 0, 0, 0);
    }

    #pragma unroll
    for (int mi = 0; mi < 2; mi++) {
        #pragma unroll
        for (int ni = 0; ni < 4; ni++) {
            int col = ni * 16 + mrow;
            float bv = bias2[col];
            #pragma unroll
            for (int rg = 0; rg < 4; rg++) {
                int row = bm + wid * 32 + mi * 16 + kg * 4 + rg;
                if (row < M) {
                    float v = acc2[mi][ni][rg] + bv;
                    H[(size_t)row * 64 + col] = (_Float16)v;
                    Y[(size_t)row * 64 + col] = (_Float16)(v * dinv[row]);
                }
            }
        }
    }
}

// ---------------------------------------------------------------------------
// APPNP propagation on scaled state y = dinv * out (weightless gathers).
// One wave per dst node; 8 lanes per edge (16B -> one 128B line per edge).
// Single MASKED 32-edge pass per iteration (clamped index + 0/1 weight).
// Last iteration fuses log_softmax and writes f32 d_out.
// [r13 lesson: channel-quartering regressed 3.5x; full-row 128B/edge at
//  ~7.7 TB/s effective is the right shape.]
// ---------------------------------------------------------------------------

template <bool LAST>
__global__ __launch_bounds__(256) void k_prop(
    const int* __restrict__ rowptr, const int* __restrict__ csr_src,
    const float* __restrict__ dinv, const _Float16* __restrict__ h,
    const _Float16* __restrict__ ycur, _Float16* __restrict__ ynxt,
    float* __restrict__ out, int N)
{
    int node = blockIdx.x * 4 + (threadIdx.x >> 6);
    if (node >= N) return;
    int lane = threadIdx.x & 63;
    int g  = lane >> 3;       // edge slot 0..7
    int cg = lane & 7;        // channel group: channels [8*cg, 8*cg+8)

    int beg = rowptr[node], end = rowptr[node + 1];
    float dn = dinv[node];
    half8 ys = *(const half8*)(ycur + ((size_t)node << 6) + cg * 8);
    half8 hv = *(const half8*)(h    + ((size_t)node << 6) + cg * 8);

    float acc[8] = {};
    for (int e = beg + g; e < end; e += 32) {
        int i1 = e + 8, i2 = e + 16, i3 = e + 24;
        float p1 = (i1 < end) ? 1.f : 0.f;
        float p2 = (i2 < end) ? 1.f : 0.f;
        float p3 = (i3 < end) ? 1.f : 0.f;
        int s0 = csr_src[e];
        int s1 = csr_src[(i1 < end) ? i1 : e];
        int s2 = csr_src[(i2 < end) ? i2 : e];
        int s3 = csr_src[(i3 < end) ? i3 : e];
        half8 v0 = *(const half8*)(ycur + ((size_t)s0 << 6) + cg * 8);
        half8 v1 = *(const half8*)(ycur + ((size_t)s1 << 6) + cg * 8);
        half8 v2 = *(const half8*)(ycur + ((size_t)s2 << 6) + cg * 8);
        half8 v3 = *(const half8*)(ycur + ((size_t)s3 << 6) + cg * 8);
        #pragma unroll
        for (int c = 0; c < 8; c++)
            acc[c] += ((float)v0[c] + p1 * (float)v1[c])
                    + (p2 * (float)v2[c] + p3 * (float)v3[c]);
    }

    #pragma unroll
    for (int c = 0; c < 8; c++) {
        float a = acc[c];
        a += __shfl_xor(a, 8);
        a += __shfl_xor(a, 16);
        a += __shfl_xor(a, 32);
        acc[c] = a;
    }

    float o[8];
    #pragma unroll
    for (int c = 0; c < 8; c++)
        o[c] = (1.0f - ALPHA) * dn * (acc[c] + (float)ys[c]) + ALPHA * (float)hv[c];

    if (!LAST) {
        if (g == 0) {
            half8 w;
            #pragma unroll
            for (int c = 0; c < 8; c++) w[c] = (_Float16)(dn * o[c]);
            *(half8*)(ynxt + ((size_t)node << 6) + cg * 8) = w;
        }
    } else {
        float m = o[0];
        #pragma unroll
        for (int c = 1; c < 8; c++) m = fmaxf(m, o[c]);
        m = fmaxf(m, __shfl_xor(m, 1));
        m = fmaxf(m, __shfl_xor(m, 2));
        m = fmaxf(m, __shfl_xor(m, 4));
        float s = 0.f;
        #pragma unroll
        for (int c = 0; c < 8; c++) s += __expf(o[c] - m);
        s += __shfl_xor(s, 1);
        s += __shfl_xor(s, 2);
        s += __shfl_xor(s, 4);
        float ls = m + logf(s);
        if (g == 0) {
            f32x4 w0, w1;
            #pragma unroll
            for (int c = 0; c < 4; c++) { w0[c] = o[c] - ls; w1[c] = o[c + 4] - ls; }
            float* p = out + ((size_t)node << 6) + cg * 8;
            *(f32x4*)p = w0;
            *(f32x4*)(p + 4) = w1;
        }
    }
}

// ---------------------------------------------------------------------------
// Launch
// ---------------------------------------------------------------------------

extern "C" void kernel_launch(void* const* d_in, const int* in_sizes, int n_in,
                              void* d_out, int out_size, void* d_ws, size_t ws_size,
                              hipStream_t stream) {
    const float* x  = (const float*)d_in[0];
    const int*   ei = (const int*)d_in[1];
    const float* W1 = (const float*)d_in[2];
    const float* b1 = (const float*)d_in[3];
    const float* W2 = (const float*)d_in[4];
    const float* b2 = (const float*)d_in[5];

    const int N = in_sizes[0] / C_IN;
    const int E = in_sizes[1] / 2;
    const int* src = ei;
    const int* dst = ei + E;

    char* ws = (char*)d_ws;
    size_t off = 0;
    auto alloc = [&](size_t bytes) -> void* {
        void* p = ws + off;
        off += (bytes + 255) & ~(size_t)255;
        return p;
    };

    int nbkt = (N + BKT_NODES - 1) / BKT_NODES;      // 196 for N=100000 (<=256 req'd)

    int*       rowptr  = (int*)      alloc((size_t)4 * (N + 1));
    float*     dinv    = (float*)    alloc((size_t)4 * N);
    int*       bcursor = (int*)      alloc((size_t)4 * nbkt);
    int*       bktbase = (int*)      alloc((size_t)4 * (nbkt + 1));
    int*       csr_src = (int*)      alloc((size_t)4 * E);
    _Float16*  W1t     = (_Float16*) alloc((size_t)2 * C_IN * C_HID);
    _Float16*  W2t     = (_Float16*) alloc((size_t)2 * C_HID * C_OUT);
    long long* bedges  = (long long*)alloc((size_t)8 * nbkt * BCAP);  // 38.5 MB
    _Float16*  h       = (_Float16*) alloc((size_t)2 * N * C_OUT);
    _Float16*  ybuf0   = (_Float16*) alloc((size_t)2 * N * C_OUT);
    _Float16*  ybuf1   = (_Float16*) alloc((size_t)2 * N * C_OUT);
    _Float16*  ybuf2   = (_Float16*) alloc((size_t)2 * N * C_OUT);

    // --- CSR build: bucket -> bucket-prefix -> fused finalize ---
    hipMemsetAsync(bcursor, 0, (size_t)4 * nbkt, stream);
    k_bucketA<<<(E + EPB - 1) / EPB, 256, 0, stream>>>(src, dst, E, bcursor, bedges, nbkt);
    k_bscan<<<1, 64, 0, stream>>>(bcursor, nbkt, bktbase, rowptr, N, E);
    k_bfin<<<nbkt, 256, 0, stream>>>(bcursor, bktbase, bedges, rowptr, dinv, csr_src, N);

    // --- weight conversion + fused MLP (f16 MFMA) ---
    int wtot = C_IN * C_HID + C_HID * C_OUT;
    k_wt<<<(wtot + 255) / 256, 256, 0, stream>>>(W1, W2, W1t, W2t);
    k_mlp<<<(N + 127) / 128, 256, 65536, stream>>>(x, W1t, W2t, b1, b2, dinv, h, ybuf0, N);

    // --- propagation on y; last iteration fuses log_softmax ---
    int pgrid = (N + 3) / 4;
    _Float16* ycur = ybuf0;
    for (int it = 0; it < K_STEPS - 1; ++it) {
        _Float16* ynxt = (it & 1) ? ybuf2 : ybuf1;
        k_prop<false><<<pgrid, 256, 0, stream>>>(rowptr, csr_src, dinv, h, ycur, ynxt, nullptr, N);
        ycur = ynxt;
    }
    k_prop<true><<<pgrid, 256, 0, stream>>>(rowptr, csr_src, dinv, h, ycur, nullptr, (float*)d_out, N);
}